// Round 13
// baseline (1308.129 us; speedup 1.0000x reference)
//
#include <hip/hip_runtime.h>

#pragma clang fp contract(off)

// ChamferLoss: BS=4, N=M=8192, D=3
// Outputs (concatenated, float):
//   [0*32768 .. )  min over gts  for each pred   [BS, M]
//   [1*32768 .. )  min over preds for each gt    [BS, N]
//   [2*32768 .. )  argmin over gts  (as float)   [BS, M]
//   [3*32768 .. )  argmin over preds (as float)  [BS, N]
//
// Bit-exact numpy fp32 emulation (PASS rounds 6-12), NO FMA anywhere
// (pragma contract(off); ROCm __f*_rn do NOT block contraction):
//   rr = ((x*x + y*y) + z*z)           ascending
//   zz = ((x0*y0 + x1*y1) + x2*y2)     ascending, no FMA
//   P  = ((rr_n + rr_m) - (2*zz))      left-to-right; *2 exact
// P operand-symmetric => both reduction directions identical bits.
// f32x2 arithmetic lowers to v_pk_*_f32 (VOP3P) = same IEEE-rn per half
// => bit-exactness preserved. (r12 lesson: scalar code costs ~35% MORE
// issue slots than packed — keep ext_vector_type(2).)
//
// Round 13: r9 structure + occupancy. SLOTS=16 x SPLITS=64 -> QBLK=128 ->
// 512 blocks = 2 blocks/CU = 8 waves/SIMD (launch_bounds(1024,8); r9 used
// 40 VGPR, fits the 64 cap). Wave spans 4 splits -> ds_read 4-way
// broadcast (1.58x on LDS pipe, not critical path).

#define BS     4
#define NPTS   8192
#define CHUNK  1024
#define BLOCK  1024
#define SPLITS 64
#define SLOTS  16                 // query slots per block
#define QT     8                  // queries per thread
#define QBLK   (SLOTS * QT)       // 128 queries per block
#define ROWS   (CHUNK / SPLITS)   // 16 candidate rows per chunk per split

typedef float f32x2 __attribute__((ext_vector_type(2)));

__global__ __launch_bounds__(BLOCK, 8)
void chamfer_kernel(const float* __restrict__ preds,
                    const float* __restrict__ gts,
                    float* __restrict__ out)
{
#pragma clang fp contract(off)
    const int dir   = blockIdx.z;  // 0: per-pred min over gts, 1: per-gt min over preds
    const int b     = blockIdx.y;
    const int t     = threadIdx.x;
    const int slot  = t & (SLOTS - 1);   // query slot within block
    const int split = t >> 4;            // candidate split (0..63)
    const int qb    = blockIdx.x * QBLK;

    const float* qbase = (dir == 0 ? preds : gts) + (size_t)b * NPTS * 3;
    const float* rbase = (dir == 0 ? gts : preds) + (size_t)b * NPTS * 3;
    float* outv = out + (size_t)dir       * BS * NPTS + (size_t)b * NPTS;
    float* outi = out + (size_t)(2 + dir) * BS * NPTS + (size_t)b * NPTS;

    // 48KB shared: [0,16K) candidate tile; after final barrier reused as
    // merge scratch: shv [SPLITS][QBLK] f32 + shi16 [SPLITS][QBLK] u16
    __shared__ alignas(16) float smem[12288];
    float (*sh)[4]        = (float (*)[4])smem;                  // [CHUNK][4]
    float *shv            = smem;                                // [SPLITS*QBLK]
    unsigned short *shi16 = (unsigned short *)(smem + 8192);

    // QT=8 query points as 4 packed groups (j = 2g+h)
    f32x2 qxv[4], qyv[4], qzv[4], rqv[4];
#pragma unroll
    for (int g = 0; g < 4; ++g) {
#pragma unroll
        for (int h = 0; h < 2; ++h) {
            const int j = g * 2 + h;
            const int q = qb + j * SLOTS + slot;
            const float x = qbase[(size_t)q * 3 + 0];
            const float y = qbase[(size_t)q * 3 + 1];
            const float z = qbase[(size_t)q * 3 + 2];
            qxv[g][h] = x; qyv[g][h] = y; qzv[g][h] = z;
            const float a0 = x * x;
            const float a1 = y * y;
            const float a2 = z * z;
            rqv[g][h] = (a0 + a1) + a2;     // ascending, no FMA
        }
    }

    float bestv[QT];
    int   besti[QT];
#pragma unroll
    for (int j = 0; j < QT; ++j) { bestv[j] = 3.0e38f; besti[j] = 0; }

    const int nchunks = NPTS / CHUNK;
    for (int c = 0; c < nchunks; ++c) {
        __syncthreads();
        {   // stage: each of 1024 threads loads one point
            const size_t n = (size_t)c * CHUNK + t;
            const float x = rbase[n * 3 + 0];
            const float y = rbase[n * 3 + 1];
            const float z = rbase[n * 3 + 2];
            sh[t][0] = x;
            sh[t][1] = y;
            sh[t][2] = z;
            const float a0 = x * x;
            const float a1 = y * y;
            const float a2 = z * z;
            sh[t][3] = (a0 + a1) + a2;     // ascending, no FMA
        }
        __syncthreads();

        const int row0 = split * ROWS;
        const int idxb = c * CHUNK + row0;
#pragma unroll 4
        for (int k = 0; k < ROWS; ++k) {
            const int row = row0 + k;
            const float x  = sh[row][0];
            const float y  = sh[row][1];
            const float z  = sh[row][2];
            const float rr = sh[row][3];
            const int idx = idxb + k;
#pragma unroll
            for (int g = 0; g < 4; ++g) {
                // zz ascending ((d0 + d1) + d2), packed IEEE-rn, no FMA
                const f32x2 p0 = qxv[g] * x;
                const f32x2 p1 = qyv[g] * y;
                const f32x2 p2 = qzv[g] * z;
                const f32x2 zz = (p0 + p1) + p2;
                const f32x2 ts = rqv[g] + rr;    // == rr + rq (commutative)
                const f32x2 w  = zz * 2.0f;
                const f32x2 v  = ts - w;
                if (v[0] < bestv[2 * g + 0]) { bestv[2 * g + 0] = v[0]; besti[2 * g + 0] = idx; }
                if (v[1] < bestv[2 * g + 1]) { bestv[2 * g + 1] = v[1]; besti[2 * g + 1] = idx; }
            }
        }
    }

    // ---- Merge over splits; lex (v, idx) min == numpy first-occurrence argmin
    // (valid: v is bit-identical regardless of which split computes it)
    __syncthreads();   // all tile reads done; safe to overwrite smem
#pragma unroll
    for (int j = 0; j < QT; ++j) {
        shv  [split * QBLK + j * SLOTS + slot] = bestv[j];
        shi16[split * QBLK + j * SLOTS + slot] = (unsigned short)besti[j];
    }
    __syncthreads();

    // 8 threads per query: each lex-merges 8 splits, then shfl_xor reduce
    const int qloc = t >> 3;       // 0..127
    const int sl   = t & 7;
    float bv = 3.0e38f;
    int   bi = 0;
#pragma unroll
    for (int k = 0; k < SPLITS / 8; ++k) {
        const int s = sl + k * 8;
        const float v2 = shv[s * QBLK + qloc];
        const int   i2 = shi16[s * QBLK + qloc];
        if (v2 < bv || (v2 == bv && i2 < bi)) { bv = v2; bi = i2; }
    }
#pragma unroll
    for (int o = 1; o < 8; o <<= 1) {
        const float ov = __shfl_xor(bv, o);
        const int   oi = __shfl_xor(bi, o);
        if (ov < bv || (ov == bv && oi < bi)) { bv = ov; bi = oi; }
    }
    if (sl == 0) {
        outv[qb + qloc] = bv;
        outi[qb + qloc] = (float)bi;
    }
}

extern "C" void kernel_launch(void* const* d_in, const int* in_sizes, int n_in,
                              void* d_out, int out_size, void* d_ws, size_t ws_size,
                              hipStream_t stream)
{
    const float* preds = (const float*)d_in[0];  // [BS, M, 3]
    const float* gts   = (const float*)d_in[1];  // [BS, N, 3]
    // d_in[2] = mask, unused (matches reference)
    float* out = (float*)d_out;

    dim3 grid(NPTS / QBLK, BS, 2);   // 64 x 4 x 2 = 512 blocks of 1024
    dim3 block(BLOCK);
    chamfer_kernel<<<grid, block, 0, stream>>>(preds, gts, out);
}

// Round 14
// 126.014 us; speedup vs baseline: 10.3808x; 10.3808x over previous
//
#include <hip/hip_runtime.h>

#pragma clang fp contract(off)

// ChamferLoss: BS=4, N=M=8192, D=3
// Outputs (concatenated, float):
//   [0*32768 .. )  min over gts  for each pred   [BS, M]
//   [1*32768 .. )  min over preds for each gt    [BS, N]
//   [2*32768 .. )  argmin over gts  (as float)   [BS, M]
//   [3*32768 .. )  argmin over preds (as float)  [BS, N]
//
// Bit-exact numpy fp32 emulation (PASS rounds 6-13), NO FMA anywhere
// (pragma contract(off); ROCm __f*_rn do NOT block contraction):
//   rr = ((x*x + y*y) + z*z)           ascending
//   zz = ((x0*y0 + x1*y1) + x2*y2)     ascending, no FMA
//   P  = ((rr_n + rr_m) - (2*zz))      left-to-right; *2 exact
// P operand-symmetric => both reduction directions identical bits.
// f32x2 lowers to v_pk_*_f32 (VOP3P), same IEEE-rn per half => bit-exact.
//
// Round 14: r13 lesson — __launch_bounds__(1024,8) FORCED the allocator to
// a 64-VGPR target and it spilled the packed query regs to scratch (5.8 GB
// traffic, VALUBusy 8%). The cap was unnecessary: natural usage is ~40 VGPR
// (r9), already <= 64, so 2 blocks/CU = 8 waves/SIMD happens from the grid
// alone. Keep 512-block geometry (SLOTS=16 x SPLITS=64, QBLK=128), bound
// back to (1024,4) = cap 128, no spill.

#define BS     4
#define NPTS   8192
#define CHUNK  1024
#define BLOCK  1024
#define SPLITS 64
#define SLOTS  16                 // query slots per block
#define QT     8                  // queries per thread
#define QBLK   (SLOTS * QT)       // 128 queries per block
#define ROWS   (CHUNK / SPLITS)   // 16 candidate rows per chunk per split

typedef float f32x2 __attribute__((ext_vector_type(2)));

__global__ __launch_bounds__(BLOCK, 4)
void chamfer_kernel(const float* __restrict__ preds,
                    const float* __restrict__ gts,
                    float* __restrict__ out)
{
#pragma clang fp contract(off)
    const int dir   = blockIdx.z;  // 0: per-pred min over gts, 1: per-gt min over preds
    const int b     = blockIdx.y;
    const int t     = threadIdx.x;
    const int slot  = t & (SLOTS - 1);   // query slot within block
    const int split = t >> 4;            // candidate split (0..63)
    const int qb    = blockIdx.x * QBLK;

    const float* qbase = (dir == 0 ? preds : gts) + (size_t)b * NPTS * 3;
    const float* rbase = (dir == 0 ? gts : preds) + (size_t)b * NPTS * 3;
    float* outv = out + (size_t)dir       * BS * NPTS + (size_t)b * NPTS;
    float* outi = out + (size_t)(2 + dir) * BS * NPTS + (size_t)b * NPTS;

    // 48KB shared: [0,16K) candidate tile; after final barrier reused as
    // merge scratch: shv [SPLITS][QBLK] f32 + shi16 [SPLITS][QBLK] u16
    __shared__ alignas(16) float smem[12288];
    float (*sh)[4]        = (float (*)[4])smem;                  // [CHUNK][4]
    float *shv            = smem;                                // [SPLITS*QBLK]
    unsigned short *shi16 = (unsigned short *)(smem + 8192);

    // QT=8 query points as 4 packed groups (j = 2g+h)
    f32x2 qxv[4], qyv[4], qzv[4], rqv[4];
#pragma unroll
    for (int g = 0; g < 4; ++g) {
#pragma unroll
        for (int h = 0; h < 2; ++h) {
            const int j = g * 2 + h;
            const int q = qb + j * SLOTS + slot;
            const float x = qbase[(size_t)q * 3 + 0];
            const float y = qbase[(size_t)q * 3 + 1];
            const float z = qbase[(size_t)q * 3 + 2];
            qxv[g][h] = x; qyv[g][h] = y; qzv[g][h] = z;
            const float a0 = x * x;
            const float a1 = y * y;
            const float a2 = z * z;
            rqv[g][h] = (a0 + a1) + a2;     // ascending, no FMA
        }
    }

    float bestv[QT];
    int   besti[QT];
#pragma unroll
    for (int j = 0; j < QT; ++j) { bestv[j] = 3.0e38f; besti[j] = 0; }

    const int nchunks = NPTS / CHUNK;
    for (int c = 0; c < nchunks; ++c) {
        __syncthreads();
        {   // stage: each of 1024 threads loads one point
            const size_t n = (size_t)c * CHUNK + t;
            const float x = rbase[n * 3 + 0];
            const float y = rbase[n * 3 + 1];
            const float z = rbase[n * 3 + 2];
            sh[t][0] = x;
            sh[t][1] = y;
            sh[t][2] = z;
            const float a0 = x * x;
            const float a1 = y * y;
            const float a2 = z * z;
            sh[t][3] = (a0 + a1) + a2;     // ascending, no FMA
        }
        __syncthreads();

        const int row0 = split * ROWS;
        const int idxb = c * CHUNK + row0;
#pragma unroll 4
        for (int k = 0; k < ROWS; ++k) {
            const int row = row0 + k;
            const float x  = sh[row][0];
            const float y  = sh[row][1];
            const float z  = sh[row][2];
            const float rr = sh[row][3];
            const int idx = idxb + k;
#pragma unroll
            for (int g = 0; g < 4; ++g) {
                // zz ascending ((d0 + d1) + d2), packed IEEE-rn, no FMA
                const f32x2 p0 = qxv[g] * x;
                const f32x2 p1 = qyv[g] * y;
                const f32x2 p2 = qzv[g] * z;
                const f32x2 zz = (p0 + p1) + p2;
                const f32x2 ts = rqv[g] + rr;    // == rr + rq (commutative)
                const f32x2 w  = zz * 2.0f;
                const f32x2 v  = ts - w;
                if (v[0] < bestv[2 * g + 0]) { bestv[2 * g + 0] = v[0]; besti[2 * g + 0] = idx; }
                if (v[1] < bestv[2 * g + 1]) { bestv[2 * g + 1] = v[1]; besti[2 * g + 1] = idx; }
            }
        }
    }

    // ---- Merge over splits; lex (v, idx) min == numpy first-occurrence argmin
    // (valid: v is bit-identical regardless of which split computes it)
    __syncthreads();   // all tile reads done; safe to overwrite smem
#pragma unroll
    for (int j = 0; j < QT; ++j) {
        shv  [split * QBLK + j * SLOTS + slot] = bestv[j];
        shi16[split * QBLK + j * SLOTS + slot] = (unsigned short)besti[j];
    }
    __syncthreads();

    // 8 threads per query: each lex-merges 8 splits, then shfl_xor reduce
    const int qloc = t >> 3;       // 0..127
    const int sl   = t & 7;
    float bv = 3.0e38f;
    int   bi = 0;
#pragma unroll
    for (int k = 0; k < SPLITS / 8; ++k) {
        const int s = sl + k * 8;
        const float v2 = shv[s * QBLK + qloc];
        const int   i2 = shi16[s * QBLK + qloc];
        if (v2 < bv || (v2 == bv && i2 < bi)) { bv = v2; bi = i2; }
    }
#pragma unroll
    for (int o = 1; o < 8; o <<= 1) {
        const float ov = __shfl_xor(bv, o);
        const int   oi = __shfl_xor(bi, o);
        if (ov < bv || (ov == bv && oi < bi)) { bv = ov; bi = oi; }
    }
    if (sl == 0) {
        outv[qb + qloc] = bv;
        outi[qb + qloc] = (float)bi;
    }
}

extern "C" void kernel_launch(void* const* d_in, const int* in_sizes, int n_in,
                              void* d_out, int out_size, void* d_ws, size_t ws_size,
                              hipStream_t stream)
{
    const float* preds = (const float*)d_in[0];  // [BS, M, 3]
    const float* gts   = (const float*)d_in[1];  // [BS, N, 3]
    // d_in[2] = mask, unused (matches reference)
    float* out = (float*)d_out;

    dim3 grid(NPTS / QBLK, BS, 2);   // 64 x 4 x 2 = 512 blocks of 1024
    dim3 block(BLOCK);
    chamfer_kernel<<<grid, block, 0, stream>>>(preds, gts, out);
}

// Round 15
// 116.858 us; speedup vs baseline: 11.1942x; 1.0784x over previous
//
#include <hip/hip_runtime.h>

#pragma clang fp contract(off)

// ChamferLoss: BS=4, N=M=8192, D=3
// Outputs (concatenated, float):
//   [0*32768 .. )  min over gts  for each pred   [BS, M]
//   [1*32768 .. )  min over preds for each gt    [BS, N]
//   [2*32768 .. )  argmin over gts  (as float)   [BS, M]
//   [3*32768 .. )  argmin over preds (as float)  [BS, N]
//
// Bit-exact numpy fp32 emulation (PASS rounds 6-14), NO FMA anywhere
// (pragma contract(off); ROCm __f*_rn do NOT block contraction):
//   rr = ((x*x + y*y) + z*z)           ascending
//   zz = ((x0*y0 + x1*y1) + x2*y2)     ascending, no FMA
//   P  = ((rr_n + rr_m) - (2*zz))      left-to-right; *2 exact
// P operand-symmetric => both reduction directions identical bits.
// f32x2 lowers to v_pk_*_f32 (VOP3P), same IEEE-rn per half => bit-exact.
//
// Round 15: back to the proven r9 geometry (SLOTS=32 x SPLITS=32, QBLK=256,
// 256 blocks — r13/r14 occupancy experiments both regressed: forced VGPR
// caps spill; 48KB-LDS 1024-thr blocks don't co-reside 2/CU anyway; and
// wave-spanning-4-splits quadruples bank conflicts). One tweak vs r9:
// CHUNK 1024->2048 (32KB tile, 2 points staged/thread) halves the barrier
// count (16 -> 8). Measured model: r9 is at ~7.9 lane-inst/pair vs 7.5
// packed floor — this is the last slack (barrier/latency stall).

#define BS     4
#define NPTS   8192
#define CHUNK  2048
#define BLOCK  1024
#define SPLITS 32
#define SLOTS  32                 // query slots per block
#define QT     8                  // queries per thread
#define QBLK   (SLOTS * QT)       // 256 queries per block
#define ROWS   (CHUNK / SPLITS)   // 64 candidate rows per chunk per split

typedef float f32x2 __attribute__((ext_vector_type(2)));

__global__ __launch_bounds__(BLOCK, 4)
void chamfer_kernel(const float* __restrict__ preds,
                    const float* __restrict__ gts,
                    float* __restrict__ out)
{
#pragma clang fp contract(off)
    const int dir   = blockIdx.z;  // 0: per-pred min over gts, 1: per-gt min over preds
    const int b     = blockIdx.y;
    const int t     = threadIdx.x;
    const int slot  = t & (SLOTS - 1);   // query slot within block
    const int split = t >> 5;            // candidate split (0..31)
    const int qb    = blockIdx.x * QBLK;

    const float* qbase = (dir == 0 ? preds : gts) + (size_t)b * NPTS * 3;
    const float* rbase = (dir == 0 ? gts : preds) + (size_t)b * NPTS * 3;
    float* outv = out + (size_t)dir       * BS * NPTS + (size_t)b * NPTS;
    float* outi = out + (size_t)(2 + dir) * BS * NPTS + (size_t)b * NPTS;

    // 48KB shared: [0,32K) candidate tile (2048 pts x 16B); after the final
    // barrier reused as merge scratch shv [32][256] f32 + shi16 [32][256] u16
    __shared__ alignas(16) float smem[12288];
    float (*sh)[4]        = (float (*)[4])smem;                  // [CHUNK][4]
    float *shv            = smem;                                // [SPLITS*QBLK]
    unsigned short *shi16 = (unsigned short *)(smem + 8192);

    // QT=8 query points as 4 packed groups (j = 2g+h)
    f32x2 qxv[4], qyv[4], qzv[4], rqv[4];
#pragma unroll
    for (int g = 0; g < 4; ++g) {
#pragma unroll
        for (int h = 0; h < 2; ++h) {
            const int j = g * 2 + h;
            const int q = qb + j * SLOTS + slot;
            const float x = qbase[(size_t)q * 3 + 0];
            const float y = qbase[(size_t)q * 3 + 1];
            const float z = qbase[(size_t)q * 3 + 2];
            qxv[g][h] = x; qyv[g][h] = y; qzv[g][h] = z;
            const float a0 = x * x;
            const float a1 = y * y;
            const float a2 = z * z;
            rqv[g][h] = (a0 + a1) + a2;     // ascending, no FMA
        }
    }

    float bestv[QT];
    int   besti[QT];
#pragma unroll
    for (int j = 0; j < QT; ++j) { bestv[j] = 3.0e38f; besti[j] = 0; }

    const int nchunks = NPTS / CHUNK;           // 4
    for (int c = 0; c < nchunks; ++c) {
        __syncthreads();
#pragma unroll
        for (int u = 0; u < CHUNK / BLOCK; ++u) {   // 2 points per thread
            const int i = u * BLOCK + t;
            const size_t n = (size_t)c * CHUNK + i;
            const float x = rbase[n * 3 + 0];
            const float y = rbase[n * 3 + 1];
            const float z = rbase[n * 3 + 2];
            sh[i][0] = x;
            sh[i][1] = y;
            sh[i][2] = z;
            const float a0 = x * x;
            const float a1 = y * y;
            const float a2 = z * z;
            sh[i][3] = (a0 + a1) + a2;     // ascending, no FMA
        }
        __syncthreads();

        const int row0 = split * ROWS;
        const int idxb = c * CHUNK + row0;
#pragma unroll 4
        for (int k = 0; k < ROWS; ++k) {
            const int row = row0 + k;
            const float x  = sh[row][0];
            const float y  = sh[row][1];
            const float z  = sh[row][2];
            const float rr = sh[row][3];
            const int idx = idxb + k;
#pragma unroll
            for (int g = 0; g < 4; ++g) {
                // zz ascending ((d0 + d1) + d2), packed IEEE-rn, no FMA
                const f32x2 p0 = qxv[g] * x;
                const f32x2 p1 = qyv[g] * y;
                const f32x2 p2 = qzv[g] * z;
                const f32x2 zz = (p0 + p1) + p2;
                const f32x2 ts = rqv[g] + rr;    // == rr + rq (commutative)
                const f32x2 w  = zz * 2.0f;
                const f32x2 v  = ts - w;
                if (v[0] < bestv[2 * g + 0]) { bestv[2 * g + 0] = v[0]; besti[2 * g + 0] = idx; }
                if (v[1] < bestv[2 * g + 1]) { bestv[2 * g + 1] = v[1]; besti[2 * g + 1] = idx; }
            }
        }
    }

    // ---- Merge over splits; lex (v, idx) min == numpy first-occurrence argmin
    // (valid: v is bit-identical regardless of which split computes it;
    //  splits cover disjoint ascending index sets)
    __syncthreads();   // all tile reads done; safe to overwrite smem
#pragma unroll
    for (int j = 0; j < QT; ++j) {
        shv  [split * QBLK + j * SLOTS + slot] = bestv[j];
        shi16[split * QBLK + j * SLOTS + slot] = (unsigned short)besti[j];
    }
    __syncthreads();

    // 4 threads per query: each lex-merges 8 splits, then shfl_xor reduce
    const int qloc = t >> 2;       // 0..255
    const int sl   = t & 3;
    float bv = 3.0e38f;
    int   bi = 0;
#pragma unroll
    for (int k = 0; k < SPLITS / 4; ++k) {
        const int s = sl + k * 4;
        const float v2 = shv[s * QBLK + qloc];
        const int   i2 = shi16[s * QBLK + qloc];
        if (v2 < bv || (v2 == bv && i2 < bi)) { bv = v2; bi = i2; }
    }
#pragma unroll
    for (int o = 1; o < 4; o <<= 1) {
        const float ov = __shfl_xor(bv, o);
        const int   oi = __shfl_xor(bi, o);
        if (ov < bv || (ov == bv && oi < bi)) { bv = ov; bi = oi; }
    }
    if (sl == 0) {
        outv[qb + qloc] = bv;
        outi[qb + qloc] = (float)bi;
    }
}

extern "C" void kernel_launch(void* const* d_in, const int* in_sizes, int n_in,
                              void* d_out, int out_size, void* d_ws, size_t ws_size,
                              hipStream_t stream)
{
    const float* preds = (const float*)d_in[0];  // [BS, M, 3]
    const float* gts   = (const float*)d_in[1];  // [BS, N, 3]
    // d_in[2] = mask, unused (matches reference)
    float* out = (float*)d_out;

    dim3 grid(NPTS / QBLK, BS, 2);   // 32 x 4 x 2 = 256 blocks of 1024
    dim3 block(BLOCK);
    chamfer_kernel<<<grid, block, 0, stream>>>(preds, gts, out);
}

// Round 16
// 116.522 us; speedup vs baseline: 11.2264x; 1.0029x over previous
//
#include <hip/hip_runtime.h>

#pragma clang fp contract(off)

// ChamferLoss: BS=4, N=M=8192, D=3
// Outputs (concatenated, float):
//   [0*32768 .. )  min over gts  for each pred   [BS, M]
//   [1*32768 .. )  min over preds for each gt    [BS, N]
//   [2*32768 .. )  argmin over gts  (as float)   [BS, M]
//   [3*32768 .. )  argmin over preds (as float)  [BS, N]
//
// Bit-exact numpy fp32 emulation (PASS rounds 6-15), NO FMA anywhere
// (pragma contract(off); ROCm __f*_rn do NOT block contraction):
//   rr = ((x*x + y*y) + z*z)           ascending
//   zz = ((x0*y0 + x1*y1) + x2*y2)     ascending, no FMA
//   P  = ((rr_n + rr_m) - (2*zz))      left-to-right; *2 exact
// P operand-symmetric => both directions identical bits. f32x2 lowers to
// v_pk_*_f32 (VOP3P), same IEEE-rn per half => bit-exact.
//
// Round 16: occupancy attack without the previous confounds. 512-thread
// blocks (hypothesis: 1024-thr groups block co-residency), candidates split
// in halves across the grid (partials in d_ws + tiny finalize kernel):
// 1024 blocks of 512 -> 4 blocks/CU = 32 waves/CU potential. Read bank
// conflicts from 4-splits-per-wave fixed by +1-row pad per 32 rows
// (slot = row + (row>>5)): split-adjacent rows land 4 banks apart,
// within-split slots stay contiguous. Lex (v,idx) everywhere = numpy
// first-occurrence.

#define BS     4
#define NPTS   8192
#define BLOCK  512
#define SLOTS  16                 // query slots per block
#define SPLITS 32                 // candidate splits per block
#define QT     8                  // queries per thread
#define QBLK   (SLOTS * QT)       // 128 queries per block
#define HALF   4096               // candidates per block (grid-split)
#define CHUNK  1024
#define ROWS   (CHUNK / SPLITS)   // 32 rows per chunk per split

typedef float f32x2 __attribute__((ext_vector_type(2)));
typedef float f32x4 __attribute__((ext_vector_type(4)));

__global__ __launch_bounds__(BLOCK, 4)
void chamfer_part(const float* __restrict__ preds,
                  const float* __restrict__ gts,
                  float* __restrict__ wsv,
                  unsigned* __restrict__ wsi)
{
#pragma clang fp contract(off)
    const int dir  = blockIdx.z & 1;   // 0: per-pred min over gts, 1: per-gt min over preds
    const int half = blockIdx.z >> 1;  // candidate half
    const int b    = blockIdx.y;
    const int qb   = blockIdx.x * QBLK;
    const int t    = threadIdx.x;
    const int slot  = t & (SLOTS - 1);
    const int split = t >> 4;          // 0..31

    const float* qbase = (dir == 0 ? preds : gts) + (size_t)b * NPTS * 3;
    const float* rbase = (dir == 0 ? gts : preds) + (size_t)b * NPTS * 3;

    // 24KB shared. Tile: padded slots (row -> row + (row>>5)), 1056 x 16B.
    // After final barrier: shv [SPLITS][QBLK] f32 + shi16 [SPLITS][QBLK] u16.
    __shared__ alignas(16) float smem[6144];
    f32x4* tile4          = (f32x4*)smem;                    // [1056]
    float* shv            = smem;                            // [4096]
    unsigned short* shi16 = (unsigned short*)(smem + 4096);  // [4096]

    // QT=8 query points as 4 packed groups (j = 2g+h)
    f32x2 qxv[4], qyv[4], qzv[4], rqv[4];
#pragma unroll
    for (int g = 0; g < 4; ++g) {
#pragma unroll
        for (int h = 0; h < 2; ++h) {
            const int j = g * 2 + h;
            const int q = qb + j * SLOTS + slot;
            const float x = qbase[(size_t)q * 3 + 0];
            const float y = qbase[(size_t)q * 3 + 1];
            const float z = qbase[(size_t)q * 3 + 2];
            qxv[g][h] = x; qyv[g][h] = y; qzv[g][h] = z;
            const float a0 = x * x;
            const float a1 = y * y;
            const float a2 = z * z;
            rqv[g][h] = (a0 + a1) + a2;     // ascending, no FMA
        }
    }

    float bestv[QT];
    int   besti[QT];
#pragma unroll
    for (int j = 0; j < QT; ++j) { bestv[j] = 3.0e38f; besti[j] = 0; }

    for (int c = 0; c < HALF / CHUNK; ++c) {       // 4 chunks
        const int n0 = half * HALF + c * CHUNK;
        __syncthreads();
#pragma unroll
        for (int u = 0; u < CHUNK / BLOCK; ++u) {  // 2 points per thread
            const int i = u * BLOCK + t;
            const size_t n = (size_t)n0 + i;
            const float x = rbase[n * 3 + 0];
            const float y = rbase[n * 3 + 1];
            const float z = rbase[n * 3 + 2];
            const float a0 = x * x;
            const float a1 = y * y;
            const float a2 = z * z;
            const float rr = (a0 + a1) + a2;       // ascending, no FMA
            const int sp = i + (i >> 5);           // padded slot
            tile4[sp] = (f32x4){x, y, z, rr};
        }
        __syncthreads();

        const int sbase = split * (ROWS + 1);      // slot base (row=split*32)
        const int idxb  = n0 + split * ROWS;       // global candidate index base
#pragma unroll 4
        for (int k = 0; k < ROWS; ++k) {
            const f32x4 cand = tile4[sbase + k];
            const float x  = cand[0];
            const float y  = cand[1];
            const float z  = cand[2];
            const float rr = cand[3];
            const int idx = idxb + k;
#pragma unroll
            for (int g = 0; g < 4; ++g) {
                // zz ascending ((d0 + d1) + d2), packed IEEE-rn, no FMA
                const f32x2 p0 = qxv[g] * x;
                const f32x2 p1 = qyv[g] * y;
                const f32x2 p2 = qzv[g] * z;
                const f32x2 zz = (p0 + p1) + p2;
                const f32x2 ts = rqv[g] + rr;      // == rr + rq (commutative)
                const f32x2 w  = zz * 2.0f;
                const f32x2 v  = ts - w;
                if (v[0] < bestv[2 * g + 0]) { bestv[2 * g + 0] = v[0]; besti[2 * g + 0] = idx; }
                if (v[1] < bestv[2 * g + 1]) { bestv[2 * g + 1] = v[1]; besti[2 * g + 1] = idx; }
            }
        }
    }

    // ---- Merge over splits (disjoint ascending ranges); lex (v,idx) min
    //      == numpy first-occurrence (v bit-identical wherever computed)
    __syncthreads();
#pragma unroll
    for (int j = 0; j < QT; ++j) {
        shv  [split * QBLK + j * SLOTS + slot] = bestv[j];
        shi16[split * QBLK + j * SLOTS + slot] = (unsigned short)besti[j];
    }
    __syncthreads();

    // 4 threads per query: each lex-merges 8 splits, then shfl_xor reduce
    const int qloc = t >> 2;       // 0..127
    const int sl   = t & 3;
    float bv = 3.0e38f;
    int   bi = 0;
#pragma unroll
    for (int k = 0; k < SPLITS / 4; ++k) {
        const int s = sl + k * 4;
        const float v2 = shv[s * QBLK + qloc];
        const int   i2 = shi16[s * QBLK + qloc];
        if (v2 < bv || (v2 == bv && i2 < bi)) { bv = v2; bi = i2; }
    }
#pragma unroll
    for (int o = 1; o < 4; o <<= 1) {
        const float ov = __shfl_xor(bv, o);
        const int   oi = __shfl_xor(bi, o);
        if (ov < bv || (ov == bv && oi < bi)) { bv = ov; bi = oi; }
    }
    if (sl == 0) {
        const size_t g = ((size_t)(dir * BS + b) * NPTS + qb + qloc);
        wsv[g * 2 + half] = bv;
        wsi[g * 2 + half] = (unsigned)bi;
    }
}

__global__ __launch_bounds__(256)
void chamfer_fin(const float* __restrict__ wsv,
                 const unsigned* __restrict__ wsi,
                 float* __restrict__ out)
{
    const int g = blockIdx.x * 256 + threadIdx.x;   // 0..65535 (dir-major)
    const float v0 = wsv[2 * g + 0];
    const float v1 = wsv[2 * g + 1];
    const unsigned i0 = wsi[2 * g + 0];
    const unsigned i1 = wsi[2 * g + 1];
    const bool take1 = (v1 < v0) || (v1 == v0 && i1 < i0);
    out[g]         = take1 ? v1 : v0;               // value outputs 0/1
    out[65536 + g] = (float)(take1 ? i1 : i0);      // argmin outputs 2/3
}

// ---------- fallback: round-15 kernel (proven PASS @116.9us) ----------
#define FCHUNK  2048
#define FBLOCK  1024
#define FSPLITS 32
#define FSLOTS  32
#define FQBLK   (FSLOTS * QT)
#define FROWS   (FCHUNK / FSPLITS)

__global__ __launch_bounds__(FBLOCK, 4)
void chamfer_single(const float* __restrict__ preds,
                    const float* __restrict__ gts,
                    float* __restrict__ out)
{
#pragma clang fp contract(off)
    const int dir   = blockIdx.z;
    const int b     = blockIdx.y;
    const int t     = threadIdx.x;
    const int slot  = t & (FSLOTS - 1);
    const int split = t >> 5;
    const int qb    = blockIdx.x * FQBLK;

    const float* qbase = (dir == 0 ? preds : gts) + (size_t)b * NPTS * 3;
    const float* rbase = (dir == 0 ? gts : preds) + (size_t)b * NPTS * 3;
    float* outv = out + (size_t)dir       * BS * NPTS + (size_t)b * NPTS;
    float* outi = out + (size_t)(2 + dir) * BS * NPTS + (size_t)b * NPTS;

    __shared__ alignas(16) float smem[12288];
    float (*sh)[4]        = (float (*)[4])smem;
    float *shv            = smem;
    unsigned short *shi16 = (unsigned short *)(smem + 8192);

    f32x2 qxv[4], qyv[4], qzv[4], rqv[4];
#pragma unroll
    for (int g = 0; g < 4; ++g) {
#pragma unroll
        for (int h = 0; h < 2; ++h) {
            const int j = g * 2 + h;
            const int q = qb + j * FSLOTS + slot;
            const float x = qbase[(size_t)q * 3 + 0];
            const float y = qbase[(size_t)q * 3 + 1];
            const float z = qbase[(size_t)q * 3 + 2];
            qxv[g][h] = x; qyv[g][h] = y; qzv[g][h] = z;
            const float a0 = x * x, a1 = y * y, a2 = z * z;
            rqv[g][h] = (a0 + a1) + a2;
        }
    }

    float bestv[QT]; int besti[QT];
#pragma unroll
    for (int j = 0; j < QT; ++j) { bestv[j] = 3.0e38f; besti[j] = 0; }

    for (int c = 0; c < NPTS / FCHUNK; ++c) {
        __syncthreads();
#pragma unroll
        for (int u = 0; u < FCHUNK / FBLOCK; ++u) {
            const int i = u * FBLOCK + t;
            const size_t n = (size_t)c * FCHUNK + i;
            const float x = rbase[n * 3 + 0];
            const float y = rbase[n * 3 + 1];
            const float z = rbase[n * 3 + 2];
            sh[i][0] = x; sh[i][1] = y; sh[i][2] = z;
            const float a0 = x * x, a1 = y * y, a2 = z * z;
            sh[i][3] = (a0 + a1) + a2;
        }
        __syncthreads();
        const int row0 = split * FROWS;
        const int idxb = c * FCHUNK + row0;
#pragma unroll 4
        for (int k = 0; k < FROWS; ++k) {
            const int row = row0 + k;
            const float x = sh[row][0], y = sh[row][1];
            const float z = sh[row][2], rr = sh[row][3];
            const int idx = idxb + k;
#pragma unroll
            for (int g = 0; g < 4; ++g) {
                const f32x2 p0 = qxv[g] * x;
                const f32x2 p1 = qyv[g] * y;
                const f32x2 p2 = qzv[g] * z;
                const f32x2 zz = (p0 + p1) + p2;
                const f32x2 ts = rqv[g] + rr;
                const f32x2 w  = zz * 2.0f;
                const f32x2 v  = ts - w;
                if (v[0] < bestv[2 * g + 0]) { bestv[2 * g + 0] = v[0]; besti[2 * g + 0] = idx; }
                if (v[1] < bestv[2 * g + 1]) { bestv[2 * g + 1] = v[1]; besti[2 * g + 1] = idx; }
            }
        }
    }

    __syncthreads();
#pragma unroll
    for (int j = 0; j < QT; ++j) {
        shv  [split * FQBLK + j * FSLOTS + slot] = bestv[j];
        shi16[split * FQBLK + j * FSLOTS + slot] = (unsigned short)besti[j];
    }
    __syncthreads();
    const int qloc = t >> 2;
    const int sl   = t & 3;
    float bv = 3.0e38f; int bi = 0;
#pragma unroll
    for (int k = 0; k < FSPLITS / 4; ++k) {
        const int s = sl + k * 4;
        const float v2 = shv[s * FQBLK + qloc];
        const int   i2 = shi16[s * FQBLK + qloc];
        if (v2 < bv || (v2 == bv && i2 < bi)) { bv = v2; bi = i2; }
    }
#pragma unroll
    for (int o = 1; o < 4; o <<= 1) {
        const float ov = __shfl_xor(bv, o);
        const int   oi = __shfl_xor(bi, o);
        if (ov < bv || (ov == bv && oi < bi)) { bv = ov; bi = oi; }
    }
    if (sl == 0) { outv[qb + qloc] = bv; outi[qb + qloc] = (float)bi; }
}

extern "C" void kernel_launch(void* const* d_in, const int* in_sizes, int n_in,
                              void* d_out, int out_size, void* d_ws, size_t ws_size,
                              hipStream_t stream)
{
    const float* preds = (const float*)d_in[0];  // [BS, M, 3]
    const float* gts   = (const float*)d_in[1];  // [BS, N, 3]
    // d_in[2] = mask, unused (matches reference)
    float* out = (float*)d_out;

    const size_t nkeys = (size_t)2 * BS * NPTS * 2;          // 131072
    const size_t need  = nkeys * (sizeof(float) + sizeof(unsigned)); // 1 MB
    if (ws_size >= need) {
        float*    wsv = (float*)d_ws;
        unsigned* wsi = (unsigned*)((float*)d_ws + nkeys);
        chamfer_part<<<dim3(NPTS / QBLK, BS, 4), BLOCK, 0, stream>>>(
            preds, gts, wsv, wsi);
        chamfer_fin<<<dim3(2 * BS * NPTS / 256), 256, 0, stream>>>(wsv, wsi, out);
    } else {
        chamfer_single<<<dim3(NPTS / FQBLK, BS, 2), FBLOCK, 0, stream>>>(
            preds, gts, out);
    }
}